// Round 3
// baseline (133.081 us; speedup 1.0000x reference)
//
#include <hip/hip_runtime.h>
#include <hip/hip_bf16.h>
#include <math.h>

// FraudDetectionNet, MFMA version.
// patch_kernel: wave = 64 patches.
//   Phase 1 (VALU): per-lane own patch -> pixel sum/sumsq + psi[16] (fp32),
//     pack to bf16, stage to LDS rows of 32 bf16 (k=0..15 real, 16..31 zero,
//     row stride 80 B).
//   Phase 2 (MFMA): per 16-patch tile: A = psi (16x32), B = U^T (32x16,
//     zero-padded K) -> re, im via 2x mfma_f32_16x16x32_bf16. prob = re^2+im^2.
//   Phase 3 (MFMA): prob (bf16, LDS roundtrip) @ Z (+-1) -> y[m][w];
//     qsum_m = sum_w w_cls[1+4p+w] * y[m][w]; scatter qsum via small LDS,
//     then R2's segmented wave reduce + atomics into per-image partials.
// final_kernel: mean/std -> tanh MLP -> + qsum -> sigmoid.
// ws: [S | SS | QS] floats (8192 each), zeroed by memsetAsync.

#define NPATCH 196
#define NIMG   8192
#define NTOTAL (NIMG * NPATCH)   // 1,605,632 = 6272 * 256
#define ROWB   80                // 32 bf16 (64B) + 16B pad

typedef __bf16 bf16x8 __attribute__((ext_vector_type(8)));
typedef float  f32x4  __attribute__((ext_vector_type(4)));

union Frag { bf16x8 v; uint4 u; unsigned us[4]; };

static __device__ inline unsigned short bfbits(float f) {
    __hip_bfloat16 h = __float2bfloat16(f);   // RNE
    unsigned short s; __builtin_memcpy(&s, &h, 2); return s;
}
static __device__ inline unsigned packbf(float lo, float hi) {
    return (unsigned)bfbits(lo) | ((unsigned)bfbits(hi) << 16);
}

__global__ __launch_bounds__(256) void patch_kernel(
    const float* __restrict__ x,        // (8192, 784)
    const float* __restrict__ U_re,     // (16,16)
    const float* __restrict__ U_im,     // (16,16)
    const float* __restrict__ w_cls,    // (785,)
    float* __restrict__ accS,
    float* __restrict__ accSS,
    float* __restrict__ accQ)
{
    __shared__ __align__(16) unsigned char lds[256 * ROWB];  // 20 KB
    __shared__ float qlds[256];

    const int tid  = threadIdx.x;
    const int lane = tid & 63;
    const int wv   = tid >> 6;
    const int n16  = lane & 15;   // MFMA col / B "n" index
    const int q    = lane >> 4;   // quad -> k-octet

    // ---- B fragments: B[k][n] with n = lane&15, k = q*8 + j ----
    Frag bre, bim, bz;
    bre.u = make_uint4(0u, 0u, 0u, 0u);
    bim.u = make_uint4(0u, 0u, 0u, 0u);
    if (q < 2) {  // k < 16 real, rest zero-padded
        const float* pr = U_re + n16 * 16 + q * 8;  // B[k][n] = U[n][k]
        const float* pi = U_im + n16 * 16 + q * 8;
        bre.us[0] = packbf(pr[0], pr[1]); bre.us[1] = packbf(pr[2], pr[3]);
        bre.us[2] = packbf(pr[4], pr[5]); bre.us[3] = packbf(pr[6], pr[7]);
        bim.us[0] = packbf(pi[0], pi[1]); bim.us[1] = packbf(pi[2], pi[3]);
        bim.us[2] = packbf(pi[4], pi[5]); bim.us[3] = packbf(pi[6], pi[7]);
    }
    #pragma unroll
    for (int jj = 0; jj < 4; ++jj) {  // Z[k][w] = 1-2*bit_{3-w}(k), wire0 = MSB
        float v0 = 0.f, v1 = 0.f;
        if (q < 2 && n16 < 4) {
            const int k0 = q * 8 + 2 * jj;
            v0 = ((k0 >> (3 - n16)) & 1) ? -1.f : 1.f;
            v1 = (((k0 + 1) >> (3 - n16)) & 1) ? -1.f : 1.f;
        }
        bz.us[jj] = packbf(v0, v1);
    }

    // ---- Phase 1: own patch -> sum/sumsq + psi -> LDS ----
    const int gp  = blockIdx.x * 256 + tid;
    const int img = gp / NPATCH;
    const int p   = gp - img * NPATCH;
    const int rr  = p / 14;
    const int cc  = p - rr * 14;

    const float* xp = x + (size_t)img * 784;
    const float2 top = *(const float2*)(xp + (2 * rr) * 28 + 2 * cc);
    const float2 bot = *(const float2*)(xp + (2 * rr + 1) * 28 + 2 * cc);
    const float x0 = top.x, x1 = top.y, x2 = bot.x, x3 = bot.y;

    const float sum   = x0 + x1 + x2 + x3;
    const float sumsq = x0 * x0 + x1 * x1 + x2 * x2 + x3 * x3;

    float s0, c0, s1, c1, s2, c2, s3, c3;
    __sincosf(0.5f * x0, &s0, &c0);
    __sincosf(0.5f * x1, &s1, &c1);
    __sincosf(0.5f * x2, &s2, &c2);
    __sincosf(0.5f * x3, &s3, &c3);

    const float a01[4] = { c0 * c1, c0 * s1, s0 * c1, s0 * s1 };
    const float a23[4] = { c2 * c3, c2 * s3, s2 * c3, s2 * s3 };

    // psi[h*4+l] = a01[h]*a23[l]; row = 16 bf16 + 16 zeros
    unsigned* row = (unsigned*)(lds + tid * ROWB);
    uint4 lo, hi;
    lo.x = packbf(a01[0] * a23[0], a01[0] * a23[1]);
    lo.y = packbf(a01[0] * a23[2], a01[0] * a23[3]);
    lo.z = packbf(a01[1] * a23[0], a01[1] * a23[1]);
    lo.w = packbf(a01[1] * a23[2], a01[1] * a23[3]);
    hi.x = packbf(a01[2] * a23[0], a01[2] * a23[1]);
    hi.y = packbf(a01[2] * a23[2], a01[2] * a23[3]);
    hi.z = packbf(a01[3] * a23[0], a01[3] * a23[1]);
    hi.w = packbf(a01[3] * a23[2], a01[3] * a23[3]);
    *(uint4*)(row)      = lo;
    *(uint4*)(row + 4)  = hi;
    *(uint4*)(row + 8)  = make_uint4(0u, 0u, 0u, 0u);
    *(uint4*)(row + 12) = make_uint4(0u, 0u, 0u, 0u);
    __syncthreads();

    // ---- Phase 2: psi @ U^T via MFMA ----
    const unsigned char* wb = lds + wv * 64 * ROWB;  // this wave's 64 rows
    f32x4 prob[4];
    #pragma unroll
    for (int t = 0; t < 4; ++t) {
        Frag a;  // A[m=n16][k=q*8+j]
        a.u = *(const uint4*)(wb + (t * 16 + n16) * ROWB + q * 16);
        f32x4 cr = {0.f, 0.f, 0.f, 0.f}, ci = {0.f, 0.f, 0.f, 0.f};
        cr = __builtin_amdgcn_mfma_f32_16x16x32_bf16(a.v, bre.v, cr, 0, 0, 0);
        ci = __builtin_amdgcn_mfma_f32_16x16x32_bf16(a.v, bim.v, ci, 0, 0, 0);
        #pragma unroll
        for (int j = 0; j < 4; ++j)
            prob[t][j] = cr[j] * cr[j] + ci[j] * ci[j];
    }
    __syncthreads();

    // write prob in A-layout rows (cols 16..31 still zero from phase 1)
    // C-layout: lane holds row m = q*4+j, col n16
    #pragma unroll
    for (int t = 0; t < 4; ++t)
        #pragma unroll
        for (int j = 0; j < 4; ++j)
            *(unsigned short*)(lds + (wv * 64 + t * 16 + q * 4 + j) * ROWB + n16 * 2)
                = bfbits(prob[t][j]);
    __syncthreads();

    // ---- Phase 3: prob @ Z via MFMA, fold classifier weights ----
    #pragma unroll
    for (int t = 0; t < 4; ++t) {
        Frag ap;
        ap.u = *(const uint4*)(wb + (t * 16 + n16) * ROWB + q * 16);
        f32x4 y = {0.f, 0.f, 0.f, 0.f};
        y = __builtin_amdgcn_mfma_f32_16x16x32_bf16(ap.v, bz.v, y, 0, 0, 0);
        // lane holds y[m=q*4+j][w=n16] (valid for n16<4)
        float v[4];
        #pragma unroll
        for (int j = 0; j < 4; ++j) {
            float wq = 0.f;
            if (n16 < 4) {
                const int gg  = blockIdx.x * 256 + wv * 64 + t * 16 + q * 4 + j;
                const int im2 = gg / NPATCH;
                const int pp  = gg - im2 * NPATCH;   // patch index within image!
                wq = w_cls[1 + 4 * pp + n16];
            }
            v[j] = y[j] * wq;
        }
        #pragma unroll
        for (int j = 0; j < 4; ++j) {   // sum over w lanes (0..3)
            v[j] += __shfl_xor(v[j], 1, 64);
            v[j] += __shfl_xor(v[j], 2, 64);
        }
        if (n16 == 0) {
            *(float4*)(qlds + wv * 64 + t * 16 + q * 4)
                = make_float4(v[0], v[1], v[2], v[3]);
        }
    }
    __syncthreads();

    const float qsum = qlds[tid];   // own patch's quantum contribution

    // ---- segmented wave reduction (<=2 images per 64-lane span) ----
    const int imgF  = __builtin_amdgcn_readfirstlane(img);
    const bool first = (img == imgF);
    float aS = first ? sum   : 0.f;  float bS = sum   - aS;
    float aV = first ? sumsq : 0.f;  float bV = sumsq - aV;
    float aQ = first ? qsum  : 0.f;  float bQ = qsum  - aQ;

    #pragma unroll
    for (int off = 1; off < 64; off <<= 1) {
        aS += __shfl_xor(aS, off, 64);  bS += __shfl_xor(bS, off, 64);
        aV += __shfl_xor(aV, off, 64);  bV += __shfl_xor(bV, off, 64);
        aQ += __shfl_xor(aQ, off, 64);  bQ += __shfl_xor(bQ, off, 64);
    }

    if (lane == 0) {
        atomicAdd(accS  + imgF, aS);
        atomicAdd(accSS + imgF, aV);
        atomicAdd(accQ  + imgF, aQ);
    }
    if (lane == 63 && img != imgF) {
        atomicAdd(accS  + img, bS);
        atomicAdd(accSS + img, bV);
        atomicAdd(accQ  + img, bQ);
    }
}

__global__ __launch_bounds__(256) void final_kernel(
    const float* __restrict__ accS,
    const float* __restrict__ accSS,
    const float* __restrict__ accQ,
    const float* __restrict__ w_in, const float* __restrict__ b_in,
    const float* __restrict__ scale_in, const float* __restrict__ shift_in,
    const float* __restrict__ Wc, const float* __restrict__ bc,
    const float* __restrict__ scalec, const float* __restrict__ shiftc,
    const float* __restrict__ w_out, const float* __restrict__ b_out,
    const float* __restrict__ w_cls, const float* __restrict__ b_cls,
    float* __restrict__ out)
{
    const int i = blockIdx.x * 256 + threadIdx.x;
    const float S  = accS[i];
    const float SS = accSS[i];
    const float QS = accQ[i];

    const float mean = S * (1.f / 784.f);
    float var = (SS - S * S * (1.f / 784.f)) * (1.f / 783.f);  // ddof=1
    var = fmaxf(var, 0.f);
    const float stdv = sqrtf(var);

    float h0 = mean, h1 = stdv;
    {
        const float t0 = tanhf(h0 * w_in[0] + h1 * w_in[1] + b_in[0]);
        const float t1 = tanhf(h0 * w_in[2] + h1 * w_in[3] + b_in[1]);
        h0 = t0 * scale_in[0] + shift_in[0];
        h1 = t1 * scale_in[1] + shift_in[1];
    }
    #pragma unroll
    for (int l = 0; l < 2; ++l) {
        const float t0 = tanhf(h0 * Wc[l * 4 + 0] + h1 * Wc[l * 4 + 1] + bc[l * 2 + 0]);
        const float t1 = tanhf(h0 * Wc[l * 4 + 2] + h1 * Wc[l * 4 + 3] + bc[l * 2 + 1]);
        h0 = t0 * scalec[l * 2 + 0] + shiftc[l * 2 + 0];
        h1 = t1 * scalec[l * 2 + 1] + shiftc[l * 2 + 1];
    }
    const float cls   = h0 * w_out[0] + h1 * w_out[1] + b_out[0];
    const float logit = b_cls[0] + w_cls[0] * cls + QS;
    out[i] = 1.f / (1.f + __expf(-logit));
}

extern "C" void kernel_launch(void* const* d_in, const int* in_sizes, int n_in,
                              void* d_out, int out_size, void* d_ws, size_t ws_size,
                              hipStream_t stream) {
    const float* x        = (const float*)d_in[0];
    const float* w_in     = (const float*)d_in[1];
    const float* b_in     = (const float*)d_in[2];
    const float* scale_in = (const float*)d_in[3];
    const float* shift_in = (const float*)d_in[4];
    const float* Wc       = (const float*)d_in[5];
    const float* bc       = (const float*)d_in[6];
    const float* scalec   = (const float*)d_in[7];
    const float* shiftc   = (const float*)d_in[8];
    const float* w_out    = (const float*)d_in[9];
    const float* b_out    = (const float*)d_in[10];
    const float* U_re     = (const float*)d_in[11];
    const float* U_im     = (const float*)d_in[12];
    const float* w_cls    = (const float*)d_in[13];
    const float* b_cls    = (const float*)d_in[14];
    float* out = (float*)d_out;

    float* accS  = (float*)d_ws;
    float* accSS = accS + NIMG;
    float* accQ  = accSS + NIMG;

    hipMemsetAsync(d_ws, 0, 3 * NIMG * sizeof(float), stream);

    patch_kernel<<<NTOTAL / 256, 256, 0, stream>>>(x, U_re, U_im, w_cls,
                                                   accS, accSS, accQ);
    final_kernel<<<NIMG / 256, 256, 0, stream>>>(accS, accSS, accQ,
                                                 w_in, b_in, scale_in, shift_in,
                                                 Wc, bc, scalec, shiftc,
                                                 w_out, b_out, w_cls, b_cls, out);
}

// Round 4
// 115.728 us; speedup vs baseline: 1.1500x; 1.1500x over previous
//
#include <hip/hip_runtime.h>
#include <hip/hip_bf16.h>
#include <math.h>

// FraudDetectionNet R4: single-dispatch MFMA version.
// Block = 1 image (256 threads, 4 waves). Patch p = tid (p<196).
//  P1 (VALU): per-lane pixel sum/sumsq + psi[16] fp32 -> bf16 -> LDS row
//     (32 bf16: k=0..15 real, 16..31 zero; row stride 80 B).
//  P2 (MFMA): per 16-patch tile: re/im = psi @ U^T via 2x mfma_f32_16x16x32_bf16
//     (verified R3 layout). prob[m][n] stays in C-layout.
//  Epilogue (in-register, NO LDS round-trip): lane (q,n16) holds prob[m][n16]
//     for m=q*4+j. zc_m(n16) = sum_w Z[n16][w]*w_cls[1+4m+w] computed with
//     per-lane constant signs (n16 bits) from an LDS-realigned w_cls copy.
//     qacc += prob*zc. One 64-lane reduce + 4-slot LDS combine at the end.
//  Thread 0: mean/std -> tanh MLP -> + qsum -> sigmoid. No ws, no atomics.

#define NPATCH 196
#define NIMG   8192
#define ROWB   80   // 32 bf16 (64B) + 16B pad; 16B-aligned rows for ds_read_b128

typedef __bf16 bf16x8 __attribute__((ext_vector_type(8)));
typedef float  f32x4  __attribute__((ext_vector_type(4)));

union Frag { bf16x8 v; uint4 u; unsigned us[4]; };

static __device__ inline unsigned short bfbits(float f) {
    __hip_bfloat16 h = __float2bfloat16(f);   // RNE
    unsigned short s; __builtin_memcpy(&s, &h, 2); return s;
}
static __device__ inline unsigned packbf(float lo, float hi) {
    return (unsigned)bfbits(lo) | ((unsigned)bfbits(hi) << 16);
}

__global__ __launch_bounds__(256) void fraud_kernel(
    const float* __restrict__ x,        // (8192, 784)
    const float* __restrict__ w_in,     // (2,2)
    const float* __restrict__ b_in,     // (2,)
    const float* __restrict__ scale_in, // (2,)
    const float* __restrict__ shift_in, // (2,)
    const float* __restrict__ Wc,       // (2,2,2)
    const float* __restrict__ bc,       // (2,2)
    const float* __restrict__ scalec,   // (2,2)
    const float* __restrict__ shiftc,   // (2,2)
    const float* __restrict__ w_out,    // (1,2)
    const float* __restrict__ b_out,    // (1,)
    const float* __restrict__ U_re,     // (16,16)
    const float* __restrict__ U_im,     // (16,16)
    const float* __restrict__ w_cls,    // (785,)
    const float* __restrict__ b_cls,    // (1,)
    float* __restrict__ out)            // (8192,)
{
    __shared__ __align__(16) unsigned char lds[256 * ROWB];  // 20 KB psi staging
    __shared__ __align__(16) float wlds[784];                // w_cls[1..784], 16B-aligned
    __shared__ float red[3][4];

    const int tid  = threadIdx.x;
    const int lane = tid & 63;
    const int wv   = tid >> 6;
    const int n16  = lane & 15;   // MFMA col index (A row m in phase-2 read; C col n)
    const int q    = lane >> 4;   // quad within wave
    const int img  = blockIdx.x;

    // stage w_cls[1..784] realigned so float4 loads at 4*m are 16B-aligned
    for (int i = tid; i < 784; i += 256) wlds[i] = w_cls[1 + i];

    // ---- B fragments: B[k][n] = U[n][k], k = q*8+j (k>=16 zero-padded) ----
    Frag bre, bim;
    bre.u = make_uint4(0u, 0u, 0u, 0u);
    bim.u = make_uint4(0u, 0u, 0u, 0u);
    if (q < 2) {
        const float* pr = U_re + n16 * 16 + q * 8;
        const float* pi = U_im + n16 * 16 + q * 8;
        bre.us[0] = packbf(pr[0], pr[1]); bre.us[1] = packbf(pr[2], pr[3]);
        bre.us[2] = packbf(pr[4], pr[5]); bre.us[3] = packbf(pr[6], pr[7]);
        bim.us[0] = packbf(pi[0], pi[1]); bim.us[1] = packbf(pi[2], pi[3]);
        bim.us[2] = packbf(pi[4], pi[5]); bim.us[3] = packbf(pi[6], pi[7]);
    }

    // ---- P1: own patch -> sum/sumsq + psi -> LDS (zeros for invalid) ----
    const float* xp = x + (size_t)img * 784;
    float sum = 0.f, sumsq = 0.f;
    uint4 lo = make_uint4(0u, 0u, 0u, 0u);
    uint4 hi = make_uint4(0u, 0u, 0u, 0u);
    if (tid < NPATCH) {
        const int rr = tid / 14;
        const int cc = tid - rr * 14;
        const float2 top = *(const float2*)(xp + (2 * rr) * 28 + 2 * cc);
        const float2 bot = *(const float2*)(xp + (2 * rr + 1) * 28 + 2 * cc);
        const float x0 = top.x, x1 = top.y, x2 = bot.x, x3 = bot.y;

        sum   = x0 + x1 + x2 + x3;
        sumsq = x0 * x0 + x1 * x1 + x2 * x2 + x3 * x3;

        float s0, c0, s1, c1, s2, c2, s3, c3;
        __sincosf(0.5f * x0, &s0, &c0);
        __sincosf(0.5f * x1, &s1, &c1);
        __sincosf(0.5f * x2, &s2, &c2);
        __sincosf(0.5f * x3, &s3, &c3);

        const float a01[4] = { c0 * c1, c0 * s1, s0 * c1, s0 * s1 };
        const float a23[4] = { c2 * c3, c2 * s3, s2 * c3, s2 * s3 };

        lo.x = packbf(a01[0] * a23[0], a01[0] * a23[1]);
        lo.y = packbf(a01[0] * a23[2], a01[0] * a23[3]);
        lo.z = packbf(a01[1] * a23[0], a01[1] * a23[1]);
        lo.w = packbf(a01[1] * a23[2], a01[1] * a23[3]);
        hi.x = packbf(a01[2] * a23[0], a01[2] * a23[1]);
        hi.y = packbf(a01[2] * a23[2], a01[2] * a23[3]);
        hi.z = packbf(a01[3] * a23[0], a01[3] * a23[1]);
        hi.w = packbf(a01[3] * a23[2], a01[3] * a23[3]);
    }
    unsigned* row = (unsigned*)(lds + tid * ROWB);
    *(uint4*)(row)      = lo;
    *(uint4*)(row + 4)  = hi;
    *(uint4*)(row + 8)  = make_uint4(0u, 0u, 0u, 0u);   // K zero-pad
    *(uint4*)(row + 12) = make_uint4(0u, 0u, 0u, 0u);
    __syncthreads();

    // ---- P2 + epilogue: MFMA then in-register Z*w_cls fold ----
    // Z[n][w] = 1 - 2*bit_{3-w}(n)  (wire 0 = MSB)
    const float sg0 = (n16 & 8) ? -1.f : 1.f;
    const float sg1 = (n16 & 4) ? -1.f : 1.f;
    const float sg2 = (n16 & 2) ? -1.f : 1.f;
    const float sg3 = (n16 & 1) ? -1.f : 1.f;

    float qacc = 0.f;
    const unsigned char* wb = lds + wv * 64 * ROWB;  // this wave's 64 rows

    auto do_tile = [&](int t) {
        Frag a;  // A[m=n16][k=q*8+j]
        a.u = *(const uint4*)(wb + (t * 16 + n16) * ROWB + q * 16);
        f32x4 cr = {0.f, 0.f, 0.f, 0.f}, ci = {0.f, 0.f, 0.f, 0.f};
        cr = __builtin_amdgcn_mfma_f32_16x16x32_bf16(a.v, bre.v, cr, 0, 0, 0);
        ci = __builtin_amdgcn_mfma_f32_16x16x32_bf16(a.v, bim.v, ci, 0, 0, 0);
        #pragma unroll
        for (int j = 0; j < 4; ++j) {
            const int m = wv * 64 + t * 16 + q * 4 + j;  // patch for C row
            float zc = 0.f;
            if (m < NPATCH) {
                const float4 wq = *(const float4*)(wlds + 4 * m);
                zc = wq.x * sg0 + wq.y * sg1 + wq.z * sg2 + wq.w * sg3;
            }
            const float prob = cr[j] * cr[j] + ci[j] * ci[j];
            qacc = fmaf(prob, zc, qacc);
        }
    };
    if (wv < 3) {           // all 4 tiles valid, m < 196 guaranteed
        do_tile(0); do_tile(1); do_tile(2); do_tile(3);
    } else {                // wave 3: only tile 0 has real patches (192..195)
        do_tile(0);
    }

    // ---- block reduction: all patches belong to this block's image ----
    #pragma unroll
    for (int off = 1; off < 64; off <<= 1) {
        sum   += __shfl_xor(sum,   off, 64);
        sumsq += __shfl_xor(sumsq, off, 64);
        qacc  += __shfl_xor(qacc,  off, 64);
    }
    if (lane == 0) {
        red[0][wv] = sum;
        red[1][wv] = sumsq;
        red[2][wv] = qacc;
    }
    __syncthreads();

    if (tid == 0) {
        const float S  = red[0][0] + red[0][1] + red[0][2] + red[0][3];
        const float SS = red[1][0] + red[1][1] + red[1][2] + red[1][3];
        const float QS = red[2][0] + red[2][1] + red[2][2] + red[2][3];

        const float mean = S * (1.f / 784.f);
        float var = (SS - S * S * (1.f / 784.f)) * (1.f / 783.f);  // ddof=1
        var = fmaxf(var, 0.f);
        const float stdv = sqrtf(var);

        float h0 = mean, h1 = stdv;
        {
            const float t0 = tanhf(h0 * w_in[0] + h1 * w_in[1] + b_in[0]);
            const float t1 = tanhf(h0 * w_in[2] + h1 * w_in[3] + b_in[1]);
            h0 = t0 * scale_in[0] + shift_in[0];
            h1 = t1 * scale_in[1] + shift_in[1];
        }
        #pragma unroll
        for (int l = 0; l < 2; ++l) {
            const float t0 = tanhf(h0 * Wc[l * 4 + 0] + h1 * Wc[l * 4 + 1] + bc[l * 2 + 0]);
            const float t1 = tanhf(h0 * Wc[l * 4 + 2] + h1 * Wc[l * 4 + 3] + bc[l * 2 + 1]);
            h0 = t0 * scalec[l * 2 + 0] + shiftc[l * 2 + 0];
            h1 = t1 * scalec[l * 2 + 1] + shiftc[l * 2 + 1];
        }
        const float cls   = h0 * w_out[0] + h1 * w_out[1] + b_out[0];
        const float logit = b_cls[0] + w_cls[0] * cls + QS;
        out[img] = 1.f / (1.f + __expf(-logit));
    }
}

extern "C" void kernel_launch(void* const* d_in, const int* in_sizes, int n_in,
                              void* d_out, int out_size, void* d_ws, size_t ws_size,
                              hipStream_t stream) {
    const float* x        = (const float*)d_in[0];
    const float* w_in     = (const float*)d_in[1];
    const float* b_in     = (const float*)d_in[2];
    const float* scale_in = (const float*)d_in[3];
    const float* shift_in = (const float*)d_in[4];
    const float* Wc       = (const float*)d_in[5];
    const float* bc       = (const float*)d_in[6];
    const float* scalec   = (const float*)d_in[7];
    const float* shiftc   = (const float*)d_in[8];
    const float* w_out    = (const float*)d_in[9];
    const float* b_out    = (const float*)d_in[10];
    const float* U_re     = (const float*)d_in[11];
    const float* U_im     = (const float*)d_in[12];
    const float* w_cls    = (const float*)d_in[13];
    const float* b_cls    = (const float*)d_in[14];
    float* out = (float*)d_out;

    fraud_kernel<<<NIMG, 256, 0, stream>>>(x, w_in, b_in, scale_in, shift_in,
                                           Wc, bc, scalec, shiftc, w_out, b_out,
                                           U_re, U_im, w_cls, b_cls, out);
}

// Round 5
// 109.426 us; speedup vs baseline: 1.2162x; 1.0576x over previous
//
#include <hip/hip_runtime.h>
#include <hip/hip_bf16.h>
#include <math.h>

// FraudDetectionNet R5: single dispatch, 16 images/block, barrier-free main loop.
// Block = 256 threads (4 waves), 16 images. Wave w owns images img0+4w..+3.
// Per wave: 12 full chunks (image im, patches c*64..c*64+63; all 64 lanes
// active, single image -> register accumulation, one reduce per image) +
// 1 tail chunk (4 images x patches 192..195 = 16 lanes).
// Each wave uses its private 64-row LDS psi region: ds_write -> lgkmcnt ->
// ds_read within the wave, NO __syncthreads in the loop.
// zc[m][n] = sum_w Z[n][w]*w_cls[1+4m+w] precomputed once per block
// (stride-17 LDS table). Epilogue: prob (MFMA C-layout) * zc -> register acc.
// Final: threads 0..15 run mean/std -> tanh MLP -> +QS -> sigmoid.

#define NPATCH 196
#define NIMG   8192
#define GIMG   16               // images per block
#define NBLK   (NIMG / GIMG)    // 512
#define ROWB   80               // 32 bf16 (64B) + 16B pad, 16B-aligned rows

typedef __bf16 bf16x8 __attribute__((ext_vector_type(8)));
typedef float  f32x4  __attribute__((ext_vector_type(4)));

union Frag { bf16x8 v; uint4 u; unsigned us[4]; };

static __device__ inline unsigned short bfbits(float f) {
    __hip_bfloat16 h = __float2bfloat16(f);   // RNE
    unsigned short s; __builtin_memcpy(&s, &h, 2); return s;
}
static __device__ inline unsigned packbf(float lo, float hi) {
    return (unsigned)bfbits(lo) | ((unsigned)bfbits(hi) << 16);
}

// psi pack from 4 pixels -> two uint4 (16 bf16)
static __device__ inline void psi_pack(float x0, float x1, float x2, float x3,
                                       uint4& lo, uint4& hi) {
    float s0, c0, s1, c1, s2, c2, s3, c3;
    __sincosf(0.5f * x0, &s0, &c0);
    __sincosf(0.5f * x1, &s1, &c1);
    __sincosf(0.5f * x2, &s2, &c2);
    __sincosf(0.5f * x3, &s3, &c3);
    const float a01[4] = { c0 * c1, c0 * s1, s0 * c1, s0 * s1 };
    const float a23[4] = { c2 * c3, c2 * s3, s2 * c3, s2 * s3 };
    lo.x = packbf(a01[0] * a23[0], a01[0] * a23[1]);
    lo.y = packbf(a01[0] * a23[2], a01[0] * a23[3]);
    lo.z = packbf(a01[1] * a23[0], a01[1] * a23[1]);
    lo.w = packbf(a01[1] * a23[2], a01[1] * a23[3]);
    hi.x = packbf(a01[2] * a23[0], a01[2] * a23[1]);
    hi.y = packbf(a01[2] * a23[2], a01[2] * a23[3]);
    hi.z = packbf(a01[3] * a23[0], a01[3] * a23[1]);
    hi.w = packbf(a01[3] * a23[2], a01[3] * a23[3]);
}

__global__ __launch_bounds__(256) void fraud_kernel(
    const float* __restrict__ x,        // (8192, 784)
    const float* __restrict__ w_in,     // (2,2)
    const float* __restrict__ b_in,     // (2,)
    const float* __restrict__ scale_in, // (2,)
    const float* __restrict__ shift_in, // (2,)
    const float* __restrict__ Wc,       // (2,2,2)
    const float* __restrict__ bc,       // (2,2)
    const float* __restrict__ scalec,   // (2,2)
    const float* __restrict__ shiftc,   // (2,2)
    const float* __restrict__ w_out,    // (1,2)
    const float* __restrict__ b_out,    // (1,)
    const float* __restrict__ U_re,     // (16,16)
    const float* __restrict__ U_im,     // (16,16)
    const float* __restrict__ w_cls,    // (785,)
    const float* __restrict__ b_cls,    // (1,)
    float* __restrict__ out)            // (8192,)
{
    __shared__ __align__(16) unsigned char lds[256 * ROWB];  // 20 KB psi rows
    __shared__ float zc[NPATCH * 17];                        // 13.3 KB
    __shared__ float accS[GIMG], accV[GIMG], accQ[GIMG];

    const int tid  = threadIdx.x;
    const int lane = tid & 63;
    const int wv   = tid >> 6;
    const int n16  = lane & 15;
    const int q    = lane >> 4;
    const int img0 = blockIdx.x * GIMG;

    // ---- zc table: zc[m*17+n] = sum_w (1-2*bit_{3-w}(n)) * w_cls[1+4m+w] ----
    for (int i = tid; i < NPATCH * 16; i += 256) {
        const int m = i >> 4, n = i & 15;
        const float* wp = w_cls + 1 + 4 * m;
        const float w0 = wp[0], w1 = wp[1], w2 = wp[2], w3 = wp[3];
        zc[m * 17 + n] = ((n & 8) ? -w0 : w0) + ((n & 4) ? -w1 : w1)
                       + ((n & 2) ? -w2 : w2) + ((n & 1) ? -w3 : w3);
    }

    // ---- B fragments: B[k][n] = U[n][k], k = q*8+j (k>=16 zero) ----
    Frag bre, bim;
    bre.u = make_uint4(0u, 0u, 0u, 0u);
    bim.u = make_uint4(0u, 0u, 0u, 0u);
    if (q < 2) {
        const float* pr = U_re + n16 * 16 + q * 8;
        const float* pi = U_im + n16 * 16 + q * 8;
        bre.us[0] = packbf(pr[0], pr[1]); bre.us[1] = packbf(pr[2], pr[3]);
        bre.us[2] = packbf(pr[4], pr[5]); bre.us[3] = packbf(pr[6], pr[7]);
        bim.us[0] = packbf(pi[0], pi[1]); bim.us[1] = packbf(pi[2], pi[3]);
        bim.us[2] = packbf(pi[4], pi[5]); bim.us[3] = packbf(pi[6], pi[7]);
    }

    // zero-pad k=16..31 of own row ONCE (never overwritten)
    unsigned char* wbase = lds + wv * 64 * ROWB;
    unsigned* myrow = (unsigned*)(wbase + lane * ROWB);
    *(uint4*)(myrow + 8)  = make_uint4(0u, 0u, 0u, 0u);
    *(uint4*)(myrow + 12) = make_uint4(0u, 0u, 0u, 0u);

    __syncthreads();   // zc table ready

    const int imgw0 = img0 + wv * 4;   // this wave's first image

    // ---- prefetch chunk idx=0 pixels (image imgw0, patch = lane) ----
    float2 ctop, cbot;
    {
        const int p = lane, rr = p / 14, cc = p - rr * 14;
        const float* xp = x + (size_t)imgw0 * 784;
        ctop = *(const float2*)(xp + (2 * rr) * 28 + 2 * cc);
        cbot = *(const float2*)(xp + (2 * rr + 1) * 28 + 2 * cc);
    }

    float rS = 0.f, rV = 0.f, rQ = 0.f;

    #pragma unroll 3
    for (int idx = 0; idx < 12; ++idx) {
        const int im = idx / 3;            // wave-local image 0..3
        const int c  = idx - im * 3;       // chunk 0..2
        const float x0 = ctop.x, x1 = ctop.y, x2 = cbot.x, x3 = cbot.y;

        // prefetch next chunk
        if (idx < 11) {
            const int nidx = idx + 1;
            const int nim = nidx / 3, nc = nidx - nim * 3;
            const int p = nc * 64 + lane, rr = p / 14, cc = p - rr * 14;
            const float* xp = x + (size_t)(imgw0 + nim) * 784;
            ctop = *(const float2*)(xp + (2 * rr) * 28 + 2 * cc);
            cbot = *(const float2*)(xp + (2 * rr + 1) * 28 + 2 * cc);
        }

        rS += x0 + x1 + x2 + x3;
        rV += x0 * x0 + x1 * x1 + x2 * x2 + x3 * x3;

        uint4 lo, hi;
        psi_pack(x0, x1, x2, x3, lo, hi);
        *(uint4*)(myrow)     = lo;
        *(uint4*)(myrow + 4) = hi;
        asm volatile("s_waitcnt lgkmcnt(0)" ::: "memory");

        #pragma unroll
        for (int t = 0; t < 4; ++t) {
            Frag a;   // A[m=n16][k=q*8+j] of this 16-row tile
            a.u = *(const uint4*)(wbase + (t * 16 + n16) * ROWB + q * 16);
            f32x4 cr = {0.f, 0.f, 0.f, 0.f}, ci = {0.f, 0.f, 0.f, 0.f};
            cr = __builtin_amdgcn_mfma_f32_16x16x32_bf16(a.v, bre.v, cr, 0, 0, 0);
            ci = __builtin_amdgcn_mfma_f32_16x16x32_bf16(a.v, bim.v, ci, 0, 0, 0);
            const int pb = (c * 64 + t * 16 + q * 4) * 17 + n16;
            #pragma unroll
            for (int j = 0; j < 4; ++j) {
                const float prob = cr[j] * cr[j] + ci[j] * ci[j];
                rQ = fmaf(prob, zc[pb + 17 * j], rQ);
            }
        }

        if (c == 2) {   // image finished: reduce & store
            #pragma unroll
            for (int off = 1; off < 64; off <<= 1) {
                rS += __shfl_xor(rS, off, 64);
                rV += __shfl_xor(rV, off, 64);
                rQ += __shfl_xor(rQ, off, 64);
            }
            if (lane == 0) {
                accS[wv * 4 + im] = rS;
                accV[wv * 4 + im] = rV;
                accQ[wv * 4 + im] = rQ;
            }
            rS = 0.f; rV = 0.f; rQ = 0.f;
        }
    }

    // ---- tail chunk: 4 images x patches 192..195, lanes 0..15 ----
    float tS = 0.f, tV = 0.f;
    if (lane < 16) {
        const int iml = lane >> 2;            // wave-local image
        const int p   = 192 + (lane & 3);
        const int rr = p / 14, cc = p - rr * 14;
        const float* xp = x + (size_t)(imgw0 + iml) * 784;
        const float2 top = *(const float2*)(xp + (2 * rr) * 28 + 2 * cc);
        const float2 bot = *(const float2*)(xp + (2 * rr + 1) * 28 + 2 * cc);
        const float x0 = top.x, x1 = top.y, x2 = bot.x, x3 = bot.y;
        tS = x0 + x1 + x2 + x3;
        tV = x0 * x0 + x1 * x1 + x2 * x2 + x3 * x3;
        uint4 lo, hi;
        psi_pack(x0, x1, x2, x3, lo, hi);
        *(uint4*)(myrow)     = lo;    // row l holds (img l>>2, patch 192+(l&3))
        *(uint4*)(myrow + 4) = hi;
    }
    asm volatile("s_waitcnt lgkmcnt(0)" ::: "memory");

    float tQ = 0.f;
    {
        Frag a;   // tile 0 only: rows 0..15
        a.u = *(const uint4*)(wbase + n16 * ROWB + q * 16);
        f32x4 cr = {0.f, 0.f, 0.f, 0.f}, ci = {0.f, 0.f, 0.f, 0.f};
        cr = __builtin_amdgcn_mfma_f32_16x16x32_bf16(a.v, bre.v, cr, 0, 0, 0);
        ci = __builtin_amdgcn_mfma_f32_16x16x32_bf16(a.v, bim.v, ci, 0, 0, 0);
        // lane (q,n16) holds prob[m=q*4+j][n16]: image q, patch 192+j
        #pragma unroll
        for (int j = 0; j < 4; ++j) {
            const float prob = cr[j] * cr[j] + ci[j] * ci[j];
            tQ = fmaf(prob, zc[(192 + j) * 17 + n16], tQ);
        }
    }
    // pixel sums: reduce within 4-lane groups (image = lane>>2 for lanes<16)
    tS += __shfl_xor(tS, 1, 64);  tS += __shfl_xor(tS, 2, 64);
    tV += __shfl_xor(tV, 1, 64);  tV += __shfl_xor(tV, 2, 64);
    // quantum: reduce within 16-lane groups (image = q)
    tQ += __shfl_xor(tQ, 1, 64);  tQ += __shfl_xor(tQ, 2, 64);
    tQ += __shfl_xor(tQ, 4, 64);  tQ += __shfl_xor(tQ, 8, 64);

    if (lane < 16 && (lane & 3) == 0) {       // one lane per image
        const int iml = lane >> 2;
        accS[wv * 4 + iml] += tS;
        accV[wv * 4 + iml] += tV;
    }
    if (n16 == 0) {                            // lanes 0,16,32,48 -> image q
        accQ[wv * 4 + q] += tQ;
    }
    __syncthreads();

    // ---- final: 16 threads, one image each ----
    if (tid < GIMG) {
        const float S  = accS[tid];
        const float SS = accV[tid];
        const float QS = accQ[tid];

        const float mean = S * (1.f / 784.f);
        float var = (SS - S * S * (1.f / 784.f)) * (1.f / 783.f);  // ddof=1
        var = fmaxf(var, 0.f);
        const float stdv = sqrtf(var);

        float h0 = mean, h1 = stdv;
        {
            const float t0 = tanhf(h0 * w_in[0] + h1 * w_in[1] + b_in[0]);
            const float t1 = tanhf(h0 * w_in[2] + h1 * w_in[3] + b_in[1]);
            h0 = t0 * scale_in[0] + shift_in[0];
            h1 = t1 * scale_in[1] + shift_in[1];
        }
        #pragma unroll
        for (int l = 0; l < 2; ++l) {
            const float t0 = tanhf(h0 * Wc[l * 4 + 0] + h1 * Wc[l * 4 + 1] + bc[l * 2 + 0]);
            const float t1 = tanhf(h0 * Wc[l * 4 + 2] + h1 * Wc[l * 4 + 3] + bc[l * 2 + 1]);
            h0 = t0 * scalec[l * 2 + 0] + shiftc[l * 2 + 0];
            h1 = t1 * scalec[l * 2 + 1] + shiftc[l * 2 + 1];
        }
        const float cls   = h0 * w_out[0] + h1 * w_out[1] + b_out[0];
        const float logit = b_cls[0] + w_cls[0] * cls + QS;
        out[img0 + tid] = 1.f / (1.f + __expf(-logit));
    }
}

extern "C" void kernel_launch(void* const* d_in, const int* in_sizes, int n_in,
                              void* d_out, int out_size, void* d_ws, size_t ws_size,
                              hipStream_t stream) {
    const float* x        = (const float*)d_in[0];
    const float* w_in     = (const float*)d_in[1];
    const float* b_in     = (const float*)d_in[2];
    const float* scale_in = (const float*)d_in[3];
    const float* shift_in = (const float*)d_in[4];
    const float* Wc       = (const float*)d_in[5];
    const float* bc       = (const float*)d_in[6];
    const float* scalec   = (const float*)d_in[7];
    const float* shiftc   = (const float*)d_in[8];
    const float* w_out    = (const float*)d_in[9];
    const float* b_out    = (const float*)d_in[10];
    const float* U_re     = (const float*)d_in[11];
    const float* U_im     = (const float*)d_in[12];
    const float* w_cls    = (const float*)d_in[13];
    const float* b_cls    = (const float*)d_in[14];
    float* out = (float*)d_out;

    fraud_kernel<<<NBLK, 256, 0, stream>>>(x, w_in, b_in, scale_in, shift_in,
                                           Wc, bc, scalec, shiftc, w_out, b_out,
                                           U_re, U_im, w_cls, b_cls, out);
}